// Round 10
// baseline (181.541 us; speedup 1.0000x reference)
//
#include <hip/hip_runtime.h>
#include <hip/hip_bf16.h>

typedef __attribute__((ext_vector_type(8))) short bf16x8;
typedef __attribute__((ext_vector_type(4))) float f32x4;
typedef __attribute__((ext_vector_type(4))) unsigned int u32x4;

#define NB 2
#define NS 2048
#define ND 768
#define NH 12
#define NHD 64
#define N3D 2304
#define NM (NB * NS)   // 4096 rows

__device__ __forceinline__ unsigned short f2bf(float x) {
    union { float f; unsigned u; } v; v.f = x;
    unsigned r = v.u + 0x7FFFu + ((v.u >> 16) & 1u);   // RNE
    return (unsigned short)(r >> 16);
}

__device__ __forceinline__ unsigned cvt_pk_bf16(float lo, float hi) {
    unsigned r;
    asm volatile("v_cvt_pk_bf16_f32 %0, %1, %2" : "=v"(r) : "v"(lo), "v"(hi));
    return r;   // D.bf16[0] = lo, D.bf16[1] = hi
}

__device__ __forceinline__ float fexp2(float x) {   // raw v_exp_f32 (2^x)
    float r;
    asm("v_exp_f32 %0, %1" : "=v"(r) : "v"(x));
    return r;
}

// ---------------------------------------------------------------------------
// Fused prep: region A = hs f32->bf16 convert (3072 blocks);
// region B = Wqkv transpose+convert (1728 blocks);
// region C = Wout transpose+convert (576 blocks).
// ---------------------------------------------------------------------------
__device__ __forceinline__ void transp_tile(const float* __restrict__ in,
                                            unsigned short* __restrict__ out,
                                            int K, int N, int nt, int kt,
                                            float (*T)[33]) {
    const int n0 = nt * 32, k0 = kt * 32;
    const int r = threadIdx.x >> 3, c4 = (threadIdx.x & 7) * 4;
    float4 v = *reinterpret_cast<const float4*>(&in[(size_t)(k0 + r) * N + n0 + c4]);
    T[r][c4 + 0] = v.x; T[r][c4 + 1] = v.y; T[r][c4 + 2] = v.z; T[r][c4 + 3] = v.w;
    __syncthreads();
    ushort4 o;
    o.x = f2bf(T[c4 + 0][r]); o.y = f2bf(T[c4 + 1][r]);
    o.z = f2bf(T[c4 + 2][r]); o.w = f2bf(T[c4 + 3][r]);
    *reinterpret_cast<ushort4*>(&out[(size_t)(n0 + r) * K + k0 + c4]) = o;
}

__global__ __launch_bounds__(256)
void prep(const float* __restrict__ hs, unsigned short* __restrict__ hsb,
          const float* __restrict__ Wqkv, unsigned short* __restrict__ W1t,
          const float* __restrict__ Wout, unsigned short* __restrict__ W2t) {
    __shared__ float T[32][33];
    const int bid = blockIdx.x;
    if (bid < 3072) {
        const int i = (bid * 256 + threadIdx.x) * 4;
        float4 v = *reinterpret_cast<const float4*>(hs + i);
        ushort4 o;
        o.x = f2bf(v.x); o.y = f2bf(v.y); o.z = f2bf(v.z); o.w = f2bf(v.w);
        *reinterpret_cast<ushort4*>(hsb + i) = o;
    } else if (bid < 3072 + 1728) {
        const int idx = bid - 3072;                 // Wqkv: 72 n-tiles x 24 k-tiles
        transp_tile(Wqkv, W1t, ND, N3D, idx % 72, idx / 72, T);
    } else {
        const int idx = bid - 4800;                 // Wout: 24 x 24
        transp_tile(Wout, W2t, ND, ND, idx % 24, idx / 24, T);
    }
}

// ---------------------------------------------------------------------------
// bf16 MFMA GEMM, K=768, m97-style single-buffer.
// EPI=0 (BM=128, BN=96 -> 768 blocks = exactly 3/CU): QKV epilogue.
//   sec 0/1: Q(*0.125*log2e)/K coalesced [B,H,S,HD].
//   sec 2:   V transposed IN-KERNEL via swizzled LDS reuse -> Vt [B,H,HD,S].
// EPI=1 (BM=64, BN=96 -> 512 blocks = 2/CU): plain epilogue -> Co f32 + bias.
// ---------------------------------------------------------------------------
template<int BM, int BN, int EPI>
__global__ __launch_bounds__(256)
void gemm_k768(const unsigned short* __restrict__ A,
               const unsigned short* __restrict__ Bt,
               const float* __restrict__ bias,
               unsigned short* __restrict__ Qo, unsigned short* __restrict__ Ko,
               unsigned short* __restrict__ Vto, float* __restrict__ Co) {
    __shared__ unsigned short SMEM[(BM + BN) * 64];
    unsigned short* As = SMEM;
    unsigned short* Bs = SMEM + BM * 64;
    const int t = threadIdx.x;
    const int wv = t >> 6, lane = t & 63;
    const int lr = lane & 15, lg = lane >> 4;
    const int wr = wv >> 1, wc = wv & 1;
    const int m0 = blockIdx.y * BM;
    const int n0 = blockIdx.x * BN;
    constexpr int FM = BM / 32;
    constexpr int FN = BN / 32;

    f32x4 acc[FM][FN];
#pragma unroll
    for (int i = 0; i < FM; ++i)
#pragma unroll
        for (int j = 0; j < FN; ++j) acc[i][j] = (f32x4){0.f, 0.f, 0.f, 0.f};

    const int sr = t >> 3;
    const int sb = t & 7;

    for (int ki = 0; ki < ND / 64; ++ki) {
        const int k0 = ki * 64;
        __syncthreads();                    // prev compute's LDS reads done
#pragma unroll
        for (int jj = 0; jj < BM / 32; ++jj) {
            const int row = jj * 32 + sr;
            __builtin_amdgcn_global_load_lds(
                (const void*)(A + (size_t)(m0 + row) * ND + k0 + ((sb ^ (row & 7)) * 8)),
                (void*)(As + jj * 2048 + wv * 512), 16, 0, 0);
        }
#pragma unroll
        for (int jj = 0; jj < BN / 32; ++jj) {
            const int row = jj * 32 + sr;
            __builtin_amdgcn_global_load_lds(
                (const void*)(Bt + (size_t)(n0 + row) * ND + k0 + ((sb ^ (row & 7)) * 8)),
                (void*)(Bs + jj * 2048 + wv * 512), 16, 0, 0);
        }
        __syncthreads();                    // staged tile visible
#pragma unroll
        for (int kc = 0; kc < 2; ++kc) {
            bf16x8 af[FM], bfr[FN];
#pragma unroll
            for (int mi = 0; mi < FM; ++mi) {
                const int row = wr * (BM / 2) + mi * 16 + lr;
                af[mi] = *(const bf16x8*)&As[row * 64 + (((kc * 4 + lg) ^ (row & 7)) * 8)];
            }
#pragma unroll
            for (int nj = 0; nj < FN; ++nj) {
                const int row = wc * (BN / 2) + nj * 16 + lr;
                bfr[nj] = *(const bf16x8*)&Bs[row * 64 + (((kc * 4 + lg) ^ (row & 7)) * 8)];
            }
#pragma unroll
            for (int mi = 0; mi < FM; ++mi)
#pragma unroll
                for (int nj = 0; nj < FN; ++nj)
                    acc[mi][nj] = __builtin_amdgcn_mfma_f32_16x16x32_bf16(
                        af[mi], bfr[nj], acc[mi][nj], 0, 0, 0);
        }
    }

    if (EPI == 0) {
        const int sec = n0 / ND;            // block-uniform
        if (sec < 2) {
#pragma unroll
            for (int mi = 0; mi < FM; ++mi) {
#pragma unroll
                for (int nj = 0; nj < FN; ++nj) {
                    const int n = n0 + wc * (BN / 2) + nj * 16 + lr;
                    const int rem = n - sec * ND;
                    const int hh = rem >> 6, dd = rem & 63;
                    const float b = bias[n];
#pragma unroll
                    for (int r = 0; r < 4; ++r) {
                        const int m = m0 + wr * (BM / 2) + mi * 16 + lg * 4 + r;
                        const int bb = m >> 11, ss = m & (NS - 1);
                        const int bhh = bb * NH + hh;
                        const float v = acc[mi][nj][r] + b;
                        if (sec == 0)   // 0.125 * log2(e): attention uses exp2
                            Qo[((size_t)bhh * NS + ss) * NHD + dd] = f2bf(v * 0.18033688011112042f);
                        else
                            Ko[((size_t)bhh * NS + ss) * NHD + dd] = f2bf(v);
                    }
                }
            }
        } else {
            // ---- V section: transpose via swizzled LDS reuse -> Vt ----
            __syncthreads();                // all MFMA LDS reads done
            char* Tb = reinterpret_cast<char*>(SMEM);
#pragma unroll
            for (int mi = 0; mi < FM; ++mi) {
#pragma unroll
                for (int nj = 0; nj < FN; ++nj) {
                    const int n_l = wc * (BN / 2) + nj * 16 + lr;
                    const int m_l = wr * (BM / 2) + mi * 16 + lg * 4;
                    const float b = bias[n0 + n_l];
                    ushort4 pk;
                    pk.x = f2bf(acc[mi][nj][0] + b);
                    pk.y = f2bf(acc[mi][nj][1] + b);
                    pk.z = f2bf(acc[mi][nj][2] + b);
                    pk.w = f2bf(acc[mi][nj][3] + b);
                    const int off = n_l * 256 + (((m_l * 2) ^ ((n_l & 15) << 4)));
                    *reinterpret_cast<ushort4*>(Tb + off) = pk;   // 8B, 2-way free
                }
            }
            __syncthreads();
            const int bb = m0 >> 11;
            const int ssb = m0 & (NS - 1);
#pragma unroll
            for (int h = 0; h < (BN * 16) / 256; ++h) {
                const int pp = t + 256 * h;
                const int n_l = pp >> 4, j = pp & 15;
                const int off = n_l * 256 + (((j ^ (n_l & 15)) << 4));
                bf16x8 v = *reinterpret_cast<const bf16x8*>(Tb + off);
                const int rem = n0 + n_l - 2 * ND;
                const int hh = rem >> 6, dd = rem & 63;
                const int bhh = bb * NH + hh;
                *reinterpret_cast<bf16x8*>(Vto + ((size_t)(bhh * NHD + dd)) * NS + ssb + 8 * j) = v;
            }
        }
    } else {
#pragma unroll
        for (int mi = 0; mi < FM; ++mi)
#pragma unroll
            for (int nj = 0; nj < FN; ++nj) {
                const int n = n0 + wc * (BN / 2) + nj * 16 + lr;
                const float b = bias[n];
#pragma unroll
                for (int r = 0; r < 4; ++r) {
                    const int m = m0 + wr * (BM / 2) + mi * 16 + lg * 4 + r;
                    Co[(size_t)m * ND + n] = acc[mi][nj][r] + b;
                }
            }
    }
}

// ---------------------------------------------------------------------------
// Causal flash attention v5:
//   * K -> REGISTERS straight from L2 (no K-LDS, no K ds_reads). Single reg
//     set kK[4][2], reloaded for round R+1 right AFTER QK^T(R) consumes it;
//     softmax+pack+PV (~400cy) covers the ~200cy L2 latency.
//   * V double-buffered in LDS (2x16KB): ONE barrier per round (was two).
//   * LDS 32KB + ~100 VGPR -> 4 blocks/CU (16 waves), was 3 (12).
//   * Balanced {63-j, j} q-tile pairing + kv-split (waves 0,1 kv-lo; 2,3
//     kv-hi) with cross-half merge via LDS overlay, as v4.
// ---------------------------------------------------------------------------
__global__ __launch_bounds__(256)
void attn_mfma(const unsigned short* __restrict__ Qg,
               const unsigned short* __restrict__ Kg,
               const unsigned short* __restrict__ Vtg,
               unsigned short* __restrict__ AO) {
    __shared__ unsigned short Vs[2][64 * 128];
    float* MRG = reinterpret_cast<float*>(Vs[0]);   // merge overlay [2][64][18]

    const int n = blockIdx.x;               // 768 blocks
    const int x = n & 7, ii = n >> 3;       // XCD = n%8
    const int bh = ((ii >> 5) << 3) + x;    // 3 heads per XCD
    const int jp = ii & 31;                 // pair index
    const int t = threadIdx.x;
    const int w = t >> 6, lane = t & 63;
    const int lr = lane & 15, lg = lane >> 4;
    const int lgp = lg & 1;
    const int qh = w & 1, p = w >> 1;       // q-half, kv-half
    const size_t bhoff = (size_t)bh * (NS * NHD);
    const unsigned short* Kb = Kg + bhoff;
    const unsigned short* Vb = Vtg + bhoff;
    const int bswz = ((lg & 1) << 1) | (lg >> 1);
    const int vsr = lane >> 4, vsb = lane & 15;
    const int bb = bh / NH, hh = bh - bb * NH;

    bf16x8 kK[4][2];                        // wave's K half, current round

#define LOADK(kvb)                                                              \
    {                                                                           \
        _Pragma("unroll")                                                       \
        for (int f = 0; f < 4; ++f)                                             \
            _Pragma("unroll")                                                   \
            for (int c = 0; c < 2; ++c)                                         \
                kK[f][c] = *(const bf16x8*)(Kb +                                \
                    (size_t)((kvb) + p * 64 + f * 16 + lr) * NHD + c * 32 + lg * 8); \
    }
#define STAGEV(buf, kvb)                                                        \
    {                                                                           \
        _Pragma("unroll")                                                       \
        for (int g = 0; g < 4; ++g) {                                           \
            const int d = g * 16 + w * 4 + vsr;                                 \
            __builtin_amdgcn_global_load_lds(                                   \
                (const void*)(Vb + (size_t)d * NS + (kvb) + ((vsb ^ (d & 7)) * 8)), \
                (void*)(Vs[buf] + (g * 16 + w * 4) * 128), 16, 0, 0);           \
        }                                                                       \
    }

#pragma unroll 1
    for (int mem = 0; mem < 2; ++mem) {
        const int qtile = mem ? jp : 63 - jp;
        const int q0 = qtile * 32;
        const int nr = qtile / 4 + 1;
        const int qrow = q0 + qh * 16 + lr;

        const unsigned short* Qp = Qg + bhoff + (size_t)qrow * NHD;
        const bf16x8 qB0 = *(const bf16x8*)(Qp + lg * 8);
        const bf16x8 qB1 = *(const bf16x8*)(Qp + 32 + lg * 8);

        float m_run = -1e30f, l_part = 0.f;
        f32x4 of[4];
#pragma unroll
        for (int f = 0; f < 4; ++f) of[f] = (f32x4){0.f, 0.f, 0.f, 0.f};

        LOADK(0);
        STAGEV(0, 0);
        __syncthreads();                    // V(0) visible (K regs by data dep)
#pragma unroll 1
        for (int R = 0; R < nr; ++R) {
            if (R + 1 < nr) STAGEV((R + 1) & 1, (R + 1) * 128);
            const unsigned short* Vc = Vs[R & 1];
            const int kvw = R * 128 + p * 64;             // wave's kv base
            const bool active = kvw <= q0 + 31;

            f32x4 sf[4];
            bf16x8 pb[2];
            if (active) {
#pragma unroll
                for (int f = 0; f < 4; ++f) sf[f] = (f32x4){0.f, 0.f, 0.f, 0.f};
                __builtin_amdgcn_s_setprio(1);
#pragma unroll
                for (int f = 0; f < 4; ++f) {
                    sf[f] = __builtin_amdgcn_mfma_f32_16x16x32_bf16(kK[f][0], qB0, sf[f], 0, 0, 0);
                    sf[f] = __builtin_amdgcn_mfma_f32_16x16x32_bf16(kK[f][1], qB1, sf[f], 0, 0, 0);
                }
                __builtin_amdgcn_s_setprio(0);
            }
            if (R + 1 < nr) LOADK((R + 1) * 128);   // reload AFTER QK^T consumed
            if (active) {
                const int rel = qrow - kvw;               // causal threshold
                if (rel < 63) {
#pragma unroll
                    for (int f = 0; f < 4; ++f)
#pragma unroll
                        for (int r = 0; r < 4; ++r)
                            if (f * 16 + lg * 4 + r > rel) sf[f][r] = -1e30f;
                }

                // ---- online softmax (exp2 domain), deferred-l ----
                float tm = -1e30f;
#pragma unroll
                for (int f = 0; f < 4; ++f)
                    tm = fmaxf(tm, fmaxf(fmaxf(sf[f][0], sf[f][1]), fmaxf(sf[f][2], sf[f][3])));
                tm = fmaxf(tm, __shfl_xor(tm, 16));
                tm = fmaxf(tm, __shfl_xor(tm, 32));
                if (!__all(tm <= m_run)) {
                    const float nm = fmaxf(m_run, tm);
                    const float corr = fexp2(m_run - nm);
                    m_run = nm;
                    l_part *= corr;
#pragma unroll
                    for (int f = 0; f < 4; ++f)
#pragma unroll
                        for (int r = 0; r < 4; ++r) of[f][r] *= corr;
                }
#pragma unroll
                for (int f = 0; f < 4; ++f)
#pragma unroll
                    for (int r = 0; r < 4; ++r) {
                        sf[f][r] = fexp2(sf[f][r] - m_run);
                        l_part += sf[f][r];
                    }

                // ---- pack P^T (sigma kv-permutation, xor16 partner swap) ----
#pragma unroll
                for (int c = 0; c < 2; ++c) {
                    const unsigned A0 = cvt_pk_bf16(sf[2 * c][0], sf[2 * c][1]);
                    const unsigned A1 = cvt_pk_bf16(sf[2 * c][2], sf[2 * c][3]);
                    const unsigned B0 = cvt_pk_bf16(sf[2 * c + 1][0], sf[2 * c + 1][1]);
                    const unsigned B1 = cvt_pk_bf16(sf[2 * c + 1][2], sf[2 * c + 1][3]);
                    const unsigned s0 = lgp ? A0 : B0;
                    const unsigned s1 = lgp ? A1 : B1;
                    const unsigned r0 = (unsigned)__shfl_xor((int)s0, 16);
                    const unsigned r1 = (unsigned)__shfl_xor((int)s1, 16);
                    const unsigned o0 = lgp ? B0 : A0;
                    const unsigned o1 = lgp ? B1 : A1;
                    u32x4 wvv;
                    wvv[0] = lgp ? r0 : o0;
                    wvv[1] = lgp ? r1 : o1;
                    wvv[2] = lgp ? o0 : r0;
                    wvv[3] = lgp ? o1 : r1;
                    pb[c] = __builtin_bit_cast(bf16x8, wvv);
                }

                // ---- O^T += Vt P^T (V from LDS, staged last round) ----
                __builtin_amdgcn_s_setprio(1);
#pragma unroll
                for (int fA = 0; fA < 4; ++fA) {
                    const int drow = fA * 16 + lr;
#pragma unroll
                    for (int c = 0; c < 2; ++c) {
                        const int blk = p * 8 + 4 * c + bswz;
                        const bf16x8 va = *(const bf16x8*)&Vc[drow * 128 + ((blk ^ (drow & 7)) * 8)];
                        of[fA] = __builtin_amdgcn_mfma_f32_16x16x32_bf16(va, pb[c], of[fA], 0, 0, 0);
                    }
                }
                __builtin_amdgcn_s_setprio(0);
            }
            __syncthreads();   // one barrier/round: drains V(R+1) writes
                               // (covered by QK^T+softmax+PV) and fences
                               // Vs[R&1] reads before round R+1 overwrites.
        }

        // ---- cross-half merge (kv halves of same q rows) ----
        l_part += __shfl_xor(l_part, 16);
        l_part += __shfl_xor(l_part, 32);
        if (p == 1) {
            float* mr = &MRG[(qh * 64 + lane) * 18];
            mr[0] = m_run; mr[1] = l_part;
#pragma unroll
            for (int f = 0; f < 4; ++f)
#pragma unroll
                for (int r = 0; r < 4; ++r) mr[2 + f * 4 + r] = of[f][r];
        }
        __syncthreads();
        if (p == 0) {
            const float* mr = &MRG[(qh * 64 + lane) * 18];
            const float m1 = mr[0], l1 = mr[1];
            const float mm = fmaxf(m_run, m1);
            const float a0 = fexp2(m_run - mm);
            const float a1 = fexp2(m1 - mm);
            const float inv = 1.f / (l_part * a0 + l1 * a1);
            unsigned short* op = AO + ((size_t)(bb * NS + qrow)) * ND + hh * NHD;
#pragma unroll
            for (int fA = 0; fA < 4; ++fA) {
                ushort4 o4;
                o4.x = f2bf((of[fA][0] * a0 + mr[2 + fA * 4 + 0] * a1) * inv);
                o4.y = f2bf((of[fA][1] * a0 + mr[2 + fA * 4 + 1] * a1) * inv);
                o4.z = f2bf((of[fA][2] * a0 + mr[2 + fA * 4 + 2] * a1) * inv);
                o4.w = f2bf((of[fA][3] * a0 + mr[2 + fA * 4 + 3] * a1) * inv);
                *reinterpret_cast<ushort4*>(op + fA * 16 + lg * 4) = o4;
            }
        }
        __syncthreads();                    // MRG reads done before next member
    }
#undef LOADK
#undef STAGEV
}

// ---------------------------------------------------------------------------
extern "C" void kernel_launch(void* const* d_in, const int* in_sizes, int n_in,
                              void* d_out, int out_size, void* d_ws, size_t ws_size,
                              hipStream_t stream) {
    const float* hs   = (const float*)d_in[0];
    const float* Wqkv = (const float*)d_in[1];
    const float* bqkv = (const float*)d_in[2];
    const float* Wout = (const float*)d_in[3];
    const float* bout = (const float*)d_in[4];
    float* out = (float*)d_out;

    char* wp = (char*)d_ws;
    unsigned short* hsb = (unsigned short*)wp; wp += (size_t)NM * ND * 2;
    unsigned short* W1t = (unsigned short*)wp; wp += (size_t)N3D * ND * 2;
    unsigned short* W2t = (unsigned short*)wp; wp += (size_t)ND * ND * 2;
    const size_t per = (size_t)NB * NH * NS * NHD;
    unsigned short* Qb  = (unsigned short*)wp; wp += per * 2;
    unsigned short* Kb  = (unsigned short*)wp; wp += per * 2;
    unsigned short* Vtb = (unsigned short*)wp; wp += per * 2;
    unsigned short* AOb = (unsigned short*)wp; wp += per * 2;

    prep<<<3072 + 1728 + 576, 256, 0, stream>>>(hs, hsb, Wqkv, W1t, Wout, W2t);

    gemm_k768<128, 96, 0><<<dim3(N3D / 96, NM / 128), 256, 0, stream>>>(
        hsb, W1t, bqkv, Qb, Kb, Vtb, nullptr);

    attn_mfma<<<768, 256, 0, stream>>>(Qb, Kb, Vtb, AOb);

    gemm_k768<64, 96, 1><<<dim3(ND / 96, NM / 64), 256, 0, stream>>>(
        AOb, W2t, bout, nullptr, nullptr, nullptr, out);
}